// Round 1
// baseline (117.337 us; speedup 1.0000x reference)
//
#include <hip/hip_runtime.h>

#define NN 8192
#define FD 128
#define BM 32
#define BK 64
#define NITER (NN / BK)   // 128
#define LDA 72            // shorts per A-tile row (144 B, pad kills bank conflicts)
#define LDB 72            // shorts per B-tile row

typedef float f32x4 __attribute__((ext_vector_type(4)));
typedef short short8 __attribute__((ext_vector_type(8)));
typedef unsigned short ushort4v __attribute__((ext_vector_type(4)));
typedef unsigned short ushort8v __attribute__((ext_vector_type(8)));

__device__ __forceinline__ unsigned short f2bf(float f) {
  unsigned int u = __builtin_bit_cast(unsigned int, f);
  u += 0x7fffu + ((u >> 16) & 1u);   // round-to-nearest-even
  return (unsigned short)(u >> 16);
}
__device__ __forceinline__ float bf2f(unsigned short h) {
  unsigned int u = ((unsigned int)h) << 16;
  return __builtin_bit_cast(float, u);
}

// -------- Kernel 1: xkT[c][r] = bf16( sum_k x[r][k] * kern[k][c] ) --------
// grid 512 blocks x 256 thr; block handles 16 rows of x, all 128 cols.
__global__ __launch_bounds__(256) void xk_kernel(
    const float* __restrict__ x, const float* __restrict__ kern,
    unsigned short* __restrict__ xkT) {
  __shared__ __align__(16) unsigned short kl[FD * FD];  // kernel in bf16, 32 KB
  __shared__ __align__(16) float xl[16 * FD];           // 16 x-rows f32, 8 KB
  const int t = threadIdx.x;
  const int row0 = blockIdx.x * 16;

  #pragma unroll
  for (int j = 0; j < 16; ++j) {              // 16384 kern elems / 256 thr
    int idx = (j * 256 + t) * 4;
    f32x4 kv = *(const f32x4*)&kern[idx];
    ushort4v kw;
    #pragma unroll
    for (int q = 0; q < 4; ++q) kw[q] = f2bf(kv[q]);
    *(ushort4v*)&kl[idx] = kw;
  }
  #pragma unroll
  for (int j = 0; j < 2; ++j) {               // 2048 x elems / 256 thr
    int idx = (j * 256 + t) * 4;
    *(f32x4*)&xl[idx] = *(const f32x4*)&x[(size_t)row0 * FD + idx];
  }
  __syncthreads();

  const int r0 = (t >> 5) * 2;                // 2 rows per thread
  const int c0 = (t & 31) * 4;                // 4 cols per thread
  float acc[2][4] = {};
  #pragma unroll 4
  for (int k = 0; k < FD; ++k) {
    ushort4v kq = *(const ushort4v*)&kl[k * FD + c0];
    float kv[4];
    #pragma unroll
    for (int q = 0; q < 4; ++q) kv[q] = bf2f(kq[q]);
    float x0 = xl[r0 * FD + k];
    float x1 = xl[(r0 + 1) * FD + k];
    #pragma unroll
    for (int q = 0; q < 4; ++q) {
      acc[0][q] += x0 * kv[q];
      acc[1][q] += x1 * kv[q];
    }
  }
  #pragma unroll
  for (int i = 0; i < 2; ++i) {
    int r = row0 + r0 + i;
    #pragma unroll
    for (int q = 0; q < 4; ++q)
      xkT[(size_t)(c0 + q) * NN + r] = f2bf(acc[i][q]);
  }
}

// -------- Kernel 2: agg = adj @ xk (bf16 MFMA) + fused rowsum/epilogue ----
// grid 256 blocks (1/CU) x 512 thr (8 waves). Block owns 32 rows x 128 cols.
__global__ __launch_bounds__(512, 2) void gcn_main(
    const float* __restrict__ adj, const unsigned short* __restrict__ xkT,
    const float* __restrict__ beta, const float* __restrict__ bias,
    float* __restrict__ out) {
  __shared__ __align__(16) unsigned short sA[2][BM * LDA];  //  9.2 KB
  __shared__ __align__(16) unsigned short sB[2][FD * LDB];  // 36.9 KB
  __shared__ float rs_lds[BM];
  __shared__ float inv_lds[BM];
  __shared__ float beta_lds[BM];

  const int t = threadIdx.x;
  const int b = blockIdx.x;
  const int bs = (b & 7) * 32 + (b >> 3);     // bijective XCD swizzle (256%8==0)
  const int row0 = bs * BM;

  const int l  = t & 63;
  const int wv = t >> 6;

  // A staging role: row ar, 4 f32 at col ac of each BK tile
  const int ar = t >> 4;                      // 0..31
  const int ac = (t & 15) * 4;                // 0..60
  const float* aptr = adj + (size_t)(row0 + ar) * NN + ac;

  // B staging role: xkT feature-rows bfr_ and bfr_+64, 8 bf16 at bk
  const int bfr_ = t >> 3;                    // 0..63
  const int bk   = (t & 7) * 8;               // 0..56
  const unsigned short* bptr0 = xkT + (size_t)bfr_ * NN + bk;
  const unsigned short* bptr1 = xkT + (size_t)(bfr_ + 64) * NN + bk;

  f32x4 areg = *(const f32x4*)aptr;
  ushort8v breg0 = *(const ushort8v*)bptr0;
  ushort8v breg1 = *(const ushort8v*)bptr1;

  f32x4 acc0 = {0.f, 0.f, 0.f, 0.f};
  f32x4 acc1 = {0.f, 0.f, 0.f, 0.f};
  float rs = 0.f;

  { // prologue: fill buffer 0
    ushort4v aw;
    #pragma unroll
    for (int j = 0; j < 4; ++j) aw[j] = f2bf(areg[j]);
    rs += areg[0] + areg[1] + areg[2] + areg[3];
    *(ushort4v*)&sA[0][ar * LDA + ac] = aw;
    *(ushort8v*)&sB[0][bfr_ * LDB + bk] = breg0;
    *(ushort8v*)&sB[0][(bfr_ + 64) * LDB + bk] = breg1;
  }
  __syncthreads();

  const int arow = l & 15;
  const int kg   = (l >> 4) * 8;
  const int cb   = wv * 16 + arow;            // this lane's output column

  int cur = 0;
  for (int kt = 1; kt <= NITER; ++kt) {
    const bool more = (kt < NITER);
    if (more) {                               // issue next tile's loads early
      areg  = *(const f32x4*)(aptr + (size_t)kt * BK);
      breg0 = *(const ushort8v*)(bptr0 + (size_t)kt * BK);
      breg1 = *(const ushort8v*)(bptr1 + (size_t)kt * BK);
    }
    const unsigned short* Ab = sA[cur];
    const unsigned short* Bb = sB[cur];
    short8 a00 = *(const short8*)&Ab[arow * LDA + kg];
    short8 a10 = *(const short8*)&Ab[(arow + 16) * LDA + kg];
    short8 a01 = *(const short8*)&Ab[arow * LDA + 32 + kg];
    short8 a11 = *(const short8*)&Ab[(arow + 16) * LDA + 32 + kg];
    short8 b0  = *(const short8*)&Bb[cb * LDB + kg];
    short8 b1  = *(const short8*)&Bb[cb * LDB + 32 + kg];
    acc0 = __builtin_amdgcn_mfma_f32_16x16x32_bf16(a00, b0, acc0, 0, 0, 0);
    acc1 = __builtin_amdgcn_mfma_f32_16x16x32_bf16(a10, b0, acc1, 0, 0, 0);
    acc0 = __builtin_amdgcn_mfma_f32_16x16x32_bf16(a01, b1, acc0, 0, 0, 0);
    acc1 = __builtin_amdgcn_mfma_f32_16x16x32_bf16(a11, b1, acc1, 0, 0, 0);
    __syncthreads();                          // all waves done reading buf cur
    if (more) {
      const int nxt = cur ^ 1;
      ushort4v aw;
      #pragma unroll
      for (int j = 0; j < 4; ++j) aw[j] = f2bf(areg[j]);
      rs += areg[0] + areg[1] + areg[2] + areg[3];
      *(ushort4v*)&sA[nxt][ar * LDA + ac] = aw;
      *(ushort8v*)&sB[nxt][bfr_ * LDB + bk] = breg0;
      *(ushort8v*)&sB[nxt][(bfr_ + 64) * LDB + bk] = breg1;
      cur = nxt;
      __syncthreads();                        // writes visible before next read
    }
  }

  // ---- rowsum reduce: 16 threads (same ar) hold disjoint column chunks ----
  rs += __shfl_xor(rs, 1, 16);
  rs += __shfl_xor(rs, 2, 16);
  rs += __shfl_xor(rs, 4, 16);
  rs += __shfl_xor(rs, 8, 16);
  if ((t & 15) == 0) rs_lds[ar] = rs;
  __syncthreads();
  if (t < BM) {
    float bt = beta[row0 + t];
    beta_lds[t] = bt;
    inv_lds[t]  = 1.0f / (rs_lds[t] + bt);
  }
  __syncthreads();

  // ---- epilogue: out = inv_deg*(agg + beta*xk) + bias ----
  const int col = cb;
  const float bias_v = bias[col];
  #pragma unroll
  for (int mf = 0; mf < 2; ++mf) {
    const f32x4 acc = mf ? acc1 : acc0;
    const int rbase = mf * 16 + ((l >> 4) << 2);   // C/D: row=(lane>>4)*4+reg
    ushort4v xv = *(const ushort4v*)&xkT[(size_t)col * NN + row0 + rbase];
    #pragma unroll
    for (int j = 0; j < 4; ++j) {
      const int r = rbase + j;
      float v = (acc[j] + beta_lds[r] * bf2f(xv[j])) * inv_lds[r] + bias_v;
      out[(size_t)(row0 + r) * FD + col] = v;
    }
  }
}

extern "C" void kernel_launch(void* const* d_in, const int* in_sizes, int n_in,
                              void* d_out, int out_size, void* d_ws, size_t ws_size,
                              hipStream_t stream) {
  const float* x    = (const float*)d_in[0];
  const float* adj  = (const float*)d_in[1];
  const float* kern = (const float*)d_in[2];
  const float* bias = (const float*)d_in[3];
  const float* beta = (const float*)d_in[4];
  float* out = (float*)d_out;
  unsigned short* xkT = (unsigned short*)d_ws;  // 128*8192*2 B = 2 MB

  hipLaunchKernelGGL(xk_kernel, dim3(NN / 16), dim3(256), 0, stream,
                     x, kern, xkT);
  hipLaunchKernelGGL(gcn_main, dim3(NN / BM), dim3(512), 0, stream,
                     adj, xkT, beta, bias, out);
}